// Round 17
// baseline (317.505 us; speedup 1.0000x reference)
//
#include <hip/hip_runtime.h>
#include <stdint.h>

#define N_NODES 4096
#define K_NN    40
#define B_CLOUDS 8
#define F_IN    8
#define H_DIM   64
#define O_DIM   128

#define OUT_FEAT_ELEMS (B_CLOUDS * N_NODES * O_DIM)   // 4194304
#define EDGES          (B_CLOUDS * N_NODES * K_NN)    // 1310720

typedef short bf16x8 __attribute__((ext_vector_type(8)));
typedef float f32x4  __attribute__((ext_vector_type(4)));

__device__ __forceinline__ unsigned short f2bf(float f) {
    unsigned u = __float_as_uint(f);
    unsigned r = (u + 0x7FFFu + ((u >> 16) & 1u)) >> 16;   // RNE
    return (unsigned short)r;
}

// wave_shr:1 — lane i receives lane i-1's value, VALU DPP (no DS round-trip).
// Lane 0 gets 0 (bound_ctrl); harmless: lane 0 sentinel always keeps.
__device__ __forceinline__ unsigned shr1_dpp(unsigned v) {
    return (unsigned)__builtin_amdgcn_update_dpp(0, (int)v, 0x138, 0xF, 0xF, true);
}

// ---------------------------------------------------------------------------
// Kernel A: exact KNN v4 — R16 (DPP select/max insert, proven 222 us) plus
// software-pipelined chunk front-end: chunk c+1's pos reads issue BEFORE
// chunk c's insert loop. The insert loop is DS-free (DPP only), so the
// compiler's lgkmcnt wait sinks to the loop bottom and the ~120-cyc LDS
// round-trip overlaps insert processing instead of serializing with it.
// ---------------------------------------------------------------------------
__global__ __launch_bounds__(1024) void knn_kernel(const float* __restrict__ pos,
                                                   float* __restrict__ out)
{
    __shared__ float px[N_NODES];
    __shared__ float py[N_NODES];
    __shared__ float pz[N_NODES];

    const int b  = blockIdx.x >> 8;           // 256 blocks per cloud
    const int i0 = (blockIdx.x & 255) << 4;   // 16 targets per block
    const float* posb = pos + (size_t)b * N_NODES * 3;

    for (int t = threadIdx.x; t < N_NODES * 3; t += 1024) {
        float v = posb[t];
        int node = t / 3;
        int c = t - node * 3;
        if (c == 0) px[node] = v;
        else if (c == 1) py[node] = v;
        else pz[node] = v;
    }
    __syncthreads();

    const int wave = threadIdx.x >> 6;
    const int lane = threadIdx.x & 63;
    const int i = i0 + wave;
    const int ci = i >> 6;        // chunk containing self
    const int li = i & 63;        // lane of self within that chunk

    const float pix = px[i], piy = py[i], piz = pz[i];

    // sorted-ascending u64 keys; lane 0 = 0-sentinel
    unsigned Rhi = (lane == 0) ? 0u : 0xFFFFFFFFu;   // d2 bits
    unsigned Rlo = (lane == 0) ? 0u : 0xFFFFFFFFu;   // index payload

    // pipeline prologue: chunk 0's pos in registers
    float cx = px[lane], cy = py[lane], cz = pz[lane];

    for (int c = 0; c < 64; ++c) {
        // prefetch chunk c+1 (wraps to 0 at the end; harmless) — the wait for
        // these sinks past the insert loop (no other DS ops in between)
        const int jn = (((c + 1) & 63) << 6) | lane;
        const float nx = px[jn];
        const float ny = py[jn];
        const float nz = pz[jn];

        const int j = (c << 6) | lane;
        // bitwise-exact fp32: ((dx*dx + dy*dy) + dz*dz), no FMA contraction
        float dx = __fsub_rn(pix, cx);
        float dy = __fsub_rn(piy, cy);
        float dz = __fsub_rn(piz, cz);
        float d2 = __fadd_rn(__fadd_rn(__fmul_rn(dx, dx), __fmul_rn(dy, dy)),
                             __fmul_rn(dz, dz));
        unsigned d2b = __float_as_uint(d2);
        if (c == ci)                       // wave-uniform: 1 of 64 chunks
            d2b = (lane == li) ? 0xFFFFFFFFu : d2b;   // self sorts after all real

        // threshold = 40th-smallest real key (lane 40; lane 0 is sentinel)
        const unsigned r40hi = (unsigned)__builtin_amdgcn_readlane((int)Rhi, 40);
        const unsigned r40lo = (unsigned)__builtin_amdgcn_readlane((int)Rlo, 40);
        const unsigned long long r40 = ((unsigned long long)r40hi << 32) | r40lo;
        const unsigned long long key = ((unsigned long long)d2b << 32) | (unsigned)j;

        unsigned long long mask = __ballot(key < r40);
        while (mask) {
            const int src = (int)__builtin_ctzll(mask);
            mask &= mask - 1;
            const unsigned long long kbjj =
                ((unsigned long long)(unsigned)__builtin_amdgcn_readlane((int)d2b, src) << 32)
                | (unsigned)((c << 6) | src);
            const unsigned long long RP = ((unsigned long long)Rhi << 32) | Rlo;
            const bool keep = (RP <= kbjj);           // prefix; lane 0 always
            const unsigned uplo = shr1_dpp(Rlo);      // VALU DPP shift-up
            const unsigned uphi = shr1_dpp(Rhi);
            const unsigned long long up = ((unsigned long long)uphi << 32) | uplo;
            const unsigned long long mx = (up > kbjj) ? up : kbjj;
            const unsigned long long nw = keep ? RP : mx;
            Rhi = (unsigned)(nw >> 32);
            Rlo = (unsigned)nw;
        }

        cx = nx; cy = ny; cz = nz;   // consume prefetch (lgkm wait lands here)
    }

    // Emit edges from lanes 1..40: src = global neighbor id, tgt = target id
    float* src_out = out + OUT_FEAT_ELEMS;
    float* tgt_out = src_out + EDGES;
    const int gi = b * N_NODES + i;
    const unsigned el = (unsigned)(lane - 1);
    if (el < K_NN) {
        src_out[(size_t)gi * K_NN + el] = (float)(b * N_NODES + (int)Rlo);
        tgt_out[(size_t)gi * K_NN + el] = (float)gi;
    }
}

// ---------------------------------------------------------------------------
// Kernel P: precompute W2 and W1 bf16 B-fragments into d_ws — R14, proven.
// ---------------------------------------------------------------------------
__global__ __launch_bounds__(256) void prep_kernel(const float* __restrict__ W2,
                                                   const float* __restrict__ W1,
                                                   unsigned short* __restrict__ ws)
{
    const int idx = blockIdx.x * 256 + threadIdx.x;   // 0..10239
    if (idx < 8192) {
        const int j    = idx & 7;
        const int lane = (idx >> 3) & 63;
        const int kt   = (idx >> 9) & 1;
        const int nt   = idx >> 10;
        const int k = kt * 32 + (lane >> 4) * 8 + j;
        const int n = nt * 16 + (lane & 15);
        ws[idx] = f2bf(W2[k * O_DIM + n]);
    } else if (idx < 8192 + 2048) {
        const int t = idx - 8192;
        const int j    = t & 7;
        const int lane = (t >> 3) & 63;
        const int nt   = t >> 9;          // 0..3
        const int k = (lane >> 4) * 8 + j;          // 0..31
        const int n = nt * 16 + (lane & 15);        // hidden channel
        ws[idx] = (k < 11) ? f2bf(W1[k * H_DIM + n]) : (unsigned short)0;
    }
}

// ---------------------------------------------------------------------------
// Kernel B: per-edge MLP, both layers MFMA — UNCHANGED from R14 (proven).
// ---------------------------------------------------------------------------
#define HSTR 72   // Hh row stride (bf16): 144 B
#define KSTR 40   // msg row stride (bf16): 80 B, 16B-aligned rows

__global__ __launch_bounds__(256, 4) void conv_kernel(
    const float* __restrict__ x, const float* __restrict__ pos,
    const unsigned short* __restrict__ w2f,   // d_ws: w2 frags [0,8192)
    const unsigned short* __restrict__ w1f,   // d_ws: w1 frags [8192,10240)
    const float* __restrict__ b1, const float* __restrict__ b2,
    float* __restrict__ out)
{
    __shared__ __align__(16) unsigned short Hh[4][48 * HSTR];    // 27648 B

    const int b    = blockIdx.x >> 10;
    const int i0   = (blockIdx.x & 1023) << 2;
    const int wave = threadIdx.x >> 6;
    const int lane = threadIdx.x & 63;
    const int quad = lane >> 4;
    const int col  = lane & 15;
    const int i    = i0 + wave;
    const int gi   = b * N_NODES + i;

    unsigned short* Hw = Hh[wave];

    // ---- phase 1: lane n (<48) gathers message row n, stages bf16 to LDS ----
    const float* src_edges = out + OUT_FEAT_ELEMS;
    if (lane < 48) {
        int j;
        if (lane < K_NN) j = (int)src_edges[(size_t)gi * K_NN + lane] - b * N_NODES;
        else             j = i;   // rows 40..47: self row + pad dups (max-safe)
        const float* xr = x + ((size_t)b * N_NODES + j) * F_IN;
        float4 xa = *(const float4*)xr;
        float4 xb = *(const float4*)(xr + 4);
        const float* pj = pos + ((size_t)b * N_NODES + j) * 3;
        const float* pi = pos + ((size_t)b * N_NODES + i) * 3;
        unsigned w[16];
#pragma unroll
        for (int t = 0; t < 16; ++t) w[t] = 0;
        w[0] = (unsigned)f2bf(xa.x) | ((unsigned)f2bf(xa.y) << 16);
        w[1] = (unsigned)f2bf(xa.z) | ((unsigned)f2bf(xa.w) << 16);
        w[2] = (unsigned)f2bf(xb.x) | ((unsigned)f2bf(xb.y) << 16);
        w[3] = (unsigned)f2bf(xb.z) | ((unsigned)f2bf(xb.w) << 16);
        w[4] = (unsigned)f2bf(pj[0] - pi[0]) | ((unsigned)f2bf(pj[1] - pi[1]) << 16);
        w[5] = (unsigned)f2bf(pj[2] - pi[2]);
        unsigned* mrow = (unsigned*)(Hw + lane * KSTR);
        *(uint4*)(mrow)      = make_uint4(w[0], w[1], w[2], w[3]);
        *(uint4*)(mrow + 4)  = make_uint4(w[4], w[5], w[6], w[7]);
        *(uint4*)(mrow + 8)  = make_uint4(w[8], w[9], w[10], w[11]);
        *(uint4*)(mrow + 12) = make_uint4(w[12], w[13], w[14], w[15]);
    }
    // same-wave ds_write -> ds_read: ordered by lgkmcnt, no barrier needed

    // ---- layer 1 via MFMA: H[48x64] = msg[48x32] . W1[32x64] ----
    bf16x8 Am[3];
#pragma unroll
    for (int mt = 0; mt < 3; ++mt)
        Am[mt] = *(const bf16x8*)&Hw[(mt * 16 + col) * KSTR + quad * 8];

    const bf16x8* W1f = (const bf16x8*)w1f;
    float hreg[12][4];
#pragma unroll
    for (int nt = 0; nt < 4; ++nt) {
        bf16x8 Bn = W1f[nt * 64 + lane];
        const float bias = b1[nt * 16 + col];
        f32x4 d0 = {bias, bias, bias, bias};
        f32x4 d1 = d0, d2 = d0;
        d0 = __builtin_amdgcn_mfma_f32_16x16x32_bf16(Am[0], Bn, d0, 0, 0, 0);
        d1 = __builtin_amdgcn_mfma_f32_16x16x32_bf16(Am[1], Bn, d1, 0, 0, 0);
        d2 = __builtin_amdgcn_mfma_f32_16x16x32_bf16(Am[2], Bn, d2, 0, 0, 0);
#pragma unroll
        for (int r = 0; r < 4; ++r) {
            hreg[nt * 3 + 0][r] = fmaxf(d0[r], 0.0f);
            hreg[nt * 3 + 1][r] = fmaxf(d1[r], 0.0f);
            hreg[nt * 3 + 2][r] = fmaxf(d2[r], 0.0f);
        }
    }

    // msg fully consumed -> overwrite region as Hh[row][hidden]
#pragma unroll
    for (int nt = 0; nt < 4; ++nt)
#pragma unroll
        for (int mt = 0; mt < 3; ++mt)
#pragma unroll
            for (int r = 0; r < 4; ++r)
                Hw[(mt * 16 + quad * 4 + r) * HSTR + nt * 16 + col] =
                    f2bf(hreg[nt * 3 + mt][r]);

    // ---- layer 2 via MFMA ----
    bf16x8 Af[3][2];
#pragma unroll
    for (int mt = 0; mt < 3; ++mt)
#pragma unroll
        for (int kt = 0; kt < 2; ++kt)
            Af[mt][kt] = *(const bf16x8*)&Hw[(mt * 16 + col) * HSTR + kt * 32 + quad * 8];

    const bf16x8* Bws = (const bf16x8*)w2f;
#pragma unroll
    for (int nt = 0; nt < 8; ++nt) {
        bf16x8 B0 = Bws[nt * 128 + lane];
        bf16x8 B1 = Bws[nt * 128 + 64 + lane];

        f32x4 c0 = {0.f, 0.f, 0.f, 0.f};
        f32x4 c1 = {0.f, 0.f, 0.f, 0.f};
        f32x4 c2 = {0.f, 0.f, 0.f, 0.f};
        c0 = __builtin_amdgcn_mfma_f32_16x16x32_bf16(Af[0][0], B0, c0, 0, 0, 0);
        c1 = __builtin_amdgcn_mfma_f32_16x16x32_bf16(Af[1][0], B0, c1, 0, 0, 0);
        c2 = __builtin_amdgcn_mfma_f32_16x16x32_bf16(Af[2][0], B0, c2, 0, 0, 0);
        c0 = __builtin_amdgcn_mfma_f32_16x16x32_bf16(Af[0][1], B1, c0, 0, 0, 0);
        c1 = __builtin_amdgcn_mfma_f32_16x16x32_bf16(Af[1][1], B1, c1, 0, 0, 0);
        c2 = __builtin_amdgcn_mfma_f32_16x16x32_bf16(Af[2][1], B1, c2, 0, 0, 0);

        float vm = c0[0];
        vm = fmaxf(vm, c0[1]); vm = fmaxf(vm, c0[2]); vm = fmaxf(vm, c0[3]);
        vm = fmaxf(vm, c1[0]); vm = fmaxf(vm, c1[1]); vm = fmaxf(vm, c1[2]); vm = fmaxf(vm, c1[3]);
        vm = fmaxf(vm, c2[0]); vm = fmaxf(vm, c2[1]); vm = fmaxf(vm, c2[2]); vm = fmaxf(vm, c2[3]);
        vm = fmaxf(vm, __shfl_xor(vm, 16));
        vm = fmaxf(vm, __shfl_xor(vm, 32));
        vm += b2[nt * 16 + col];

        if (lane < 16) out[(size_t)gi * O_DIM + nt * 16 + lane] = vm;
    }
}

// ---------------------------------------------------------------------------
extern "C" void kernel_launch(void* const* d_in, const int* in_sizes, int n_in,
                              void* d_out, int out_size, void* d_ws, size_t ws_size,
                              hipStream_t stream) {
    const float* x   = (const float*)d_in[0];
    const float* pos = (const float*)d_in[1];
    const float* W1  = (const float*)d_in[2];
    const float* b1  = (const float*)d_in[3];
    const float* W2  = (const float*)d_in[4];
    const float* b2  = (const float*)d_in[5];
    float* out = (float*)d_out;
    unsigned short* ws = (unsigned short*)d_ws;   // 10240 bf16 = 20.5 KB

    prep_kernel<<<40, 256, 0, stream>>>(W2, W1, ws);
    knn_kernel<<<(B_CLOUDS * N_NODES) / 16, 1024, 0, stream>>>(pos, out);
    conv_kernel<<<(B_CLOUDS * N_NODES) / 4, 256, 0, stream>>>(
        x, pos, ws, ws + 8192, b1, b2, out);
}